// Round 1
// 621.469 us; speedup vs baseline: 1.3657x; 1.3657x over previous
//
#include <hip/hip_runtime.h>
#include <math.h>

#define HH 512
#define WW 512
#define NBATCH 64
#define PLANE (HH * WW)  // 262144

// ---------------- v2 rolling-register conv geometry ----------------
#define TH2 16                        // rows per wave-strip
#define NSTRIP (HH / TH2)             // 32
#define NWAVE (NBATCH * NSTRIP * 2)   // 4096 waves (2 col-segments of 256)
#define NBLK2 (NWAVE / 4)             // 1024 blocks x 256 thr
#define NPART NBLK2

// ---------------- legacy (fallback) geometry ----------------
#define TW 64
#define TH 16
#define NTILES (NBATCH * 8 * 32)  // 16384
#define NTHR 256
#define XT_H (TH + 4)
#define XT_W (TW + 4)
#define ZT_H (TH + 2)
#define ZT_W (TW + 2)
#define X1_H (TH + 2)
#define X1_W (TW + 2)

#define Y1_ELEMS ((size_t)NBATCH * 3 * HH * WW)  // 50331648
// keep the OLD (larger) bound so path selection matches the proven session
#define WS_FAST_BYTES ((Y1_ELEMS + (size_t)NTILES * 6 + 16) * 4)

// rational 'A': P(x)/(1+|Q(x)|), deg P=5, deg Q=4 no constant term
__device__ __forceinline__ float ratf(float v, const float* A, const float* B) {
  float p = fmaf(v, A[5], A[4]);
  p = fmaf(v, p, A[3]);
  p = fmaf(v, p, A[2]);
  p = fmaf(v, p, A[1]);
  p = fmaf(v, p, A[0]);
  float q = fmaf(v, B[3], B[2]);
  q = fmaf(v, q, B[1]);
  q = fmaf(v, q, B[0]);
  q *= v;
  float den = 1.0f + fabsf(q);
  return p * __builtin_amdgcn_rcpf(den);
}

__device__ __forceinline__ void block_reduce6_store(float s[6], float* __restrict__ dst) {
  __shared__ float red[4][6];
#pragma unroll
  for (int k = 0; k < 6; ++k) {
    float v = s[k];
#pragma unroll
    for (int off = 32; off; off >>= 1) v += __shfl_down(v, off, 64);
    s[k] = v;
  }
  int lane = threadIdx.x & 63, wv = threadIdx.x >> 6;
  if (lane == 0) {
#pragma unroll
    for (int k = 0; k < 6; ++k) red[wv][k] = s[k];
  }
  __syncthreads();
  if (threadIdx.x < 6) {
    dst[threadIdx.x] = red[0][threadIdx.x] + red[1][threadIdx.x] + red[2][threadIdx.x] + red[3][threadIdx.x];
  }
}

// ---------------- reduce partials -> scale/shift (6 floats) ----------------
__global__ __launch_bounds__(256) void k_reduce(const float* __restrict__ partials, int n,
                                                const float* __restrict__ gamma,
                                                const float* __restrict__ beta,
                                                float* __restrict__ out6) {
  double s[6] = {0, 0, 0, 0, 0, 0};
  for (int j = threadIdx.x; j < n; j += 256) {
    const float* p = partials + (size_t)j * 6;
#pragma unroll
    for (int k = 0; k < 6; ++k) s[k] += (double)p[k];
  }
  __shared__ double red[256];
  __shared__ double tot[6];
  for (int k = 0; k < 6; ++k) {
    red[threadIdx.x] = s[k];
    __syncthreads();
    for (int off = 128; off; off >>= 1) {
      if (threadIdx.x < off) red[threadIdx.x] += red[threadIdx.x + off];
      __syncthreads();
    }
    if (threadIdx.x == 0) tot[k] = red[0];
    __syncthreads();
  }
  if (threadIdx.x < 3) {
    int c = threadIdx.x;
    double N = 16777216.0;  // 64*512*512
    double mean = tot[c] / N;
    double var = tot[3 + c] / N - mean * mean;
    double sc = (double)gamma[c] / sqrt(var + 1e-5);
    double sh = (double)beta[c] - mean * sc;
    out6[c] = (float)sc;
    out6[3 + c] = (float)sh;
  }
}

// =============== FAST PATH v2: rolling-register line convs =================

struct LRow {
  float4 v;  // 4 cols at c0..c0+3
  float e;   // edge scalar (only meaningful on elane)
  bool ok;   // row inside image
};
struct FRow {
  float4 v;
  float L, R;  // cols c0-1 and c0+4
};

__device__ __forceinline__ LRow load_row(const float* __restrict__ base, int gh, int c0,
                                         int lane, int elane, int eoff) {
  LRow r;
  r.v = make_float4(0.f, 0.f, 0.f, 0.f);
  r.e = 0.f;
  r.ok = ((unsigned)gh < (unsigned)HH);
  if (r.ok) {
    const float* p = base + (size_t)gh * WW + c0;
    r.v = *(const float4*)p;
    if (lane == elane) r.e = p[eoff];
  }
  return r;
}

// finalize for conv1: derive L/R from shuffles (+ preloaded edge scalar)
__device__ __forceinline__ FRow fin1(const LRow& n, int lane, bool leftSeg) {
  FRow f;
  f.v = n.v;
  float Lp = __shfl_up(n.v.w, 1);
  float Rp = __shfl_down(n.v.x, 1);
  f.L = (lane == 0) ? (leftSeg ? 0.f : n.e) : Lp;
  f.R = (lane == 63) ? (leftSeg ? n.e : 0.f) : Rp;
  return f;
}

// finalize for conv2: z = rational(bn1(y1)) applied BEFORE shuffles; padding stays 0
__device__ __forceinline__ FRow fin2(const LRow& n, int lane, bool leftSeg,
                                     float sc, float sh, const float* A, const float* B) {
  FRow f;
  if (!n.ok) {
    f.v = make_float4(0.f, 0.f, 0.f, 0.f);
    f.L = 0.f;
    f.R = 0.f;
    return f;
  }
  float4 z;
  z.x = ratf(fmaf(n.v.x, sc, sh), A, B);
  z.y = ratf(fmaf(n.v.y, sc, sh), A, B);
  z.z = ratf(fmaf(n.v.z, sc, sh), A, B);
  z.w = ratf(fmaf(n.v.w, sc, sh), A, B);
  float et = ratf(fmaf(n.e, sc, sh), A, B);
  float Lp = __shfl_up(z.w, 1);
  float Rp = __shfl_down(z.x, 1);
  f.v = z;
  f.L = (lane == 0) ? (leftSeg ? 0.f : et) : Lp;
  f.R = (lane == 63) ? (leftSeg ? et : 0.f) : Rp;
  return f;
}

// 3x3x3 conv on a finalized 3-row window -> 4 cols x 3 out-channels (324 FMA)
__device__ __forceinline__ void conv_accum(const FRow (&F)[3][3], const float (&wr)[3][3][3][3],
                                           float4 (&acc)[3]) {
#pragma unroll
  for (int ci = 0; ci < 3; ++ci)
#pragma unroll
    for (int ky = 0; ky < 3; ++ky) {
      float s0 = F[ci][ky].L;
      float s1 = F[ci][ky].v.x;
      float s2 = F[ci][ky].v.y;
      float s3 = F[ci][ky].v.z;
      float s4 = F[ci][ky].v.w;
      float s5 = F[ci][ky].R;
#pragma unroll
      for (int co = 0; co < 3; ++co) {
        float w0 = wr[co][ci][ky][0], w1_ = wr[co][ci][ky][1], w2_ = wr[co][ci][ky][2];
        acc[co].x = fmaf(w0, s0, acc[co].x);
        acc[co].x = fmaf(w1_, s1, acc[co].x);
        acc[co].x = fmaf(w2_, s2, acc[co].x);
        acc[co].y = fmaf(w0, s1, acc[co].y);
        acc[co].y = fmaf(w1_, s2, acc[co].y);
        acc[co].y = fmaf(w2_, s3, acc[co].y);
        acc[co].z = fmaf(w0, s2, acc[co].z);
        acc[co].z = fmaf(w1_, s3, acc[co].z);
        acc[co].z = fmaf(w2_, s4, acc[co].z);
        acc[co].w = fmaf(w0, s3, acc[co].w);
        acc[co].w = fmaf(w1_, s4, acc[co].w);
        acc[co].w = fmaf(w2_, s5, acc[co].w);
      }
    }
}

// P1: conv1 -> y1 + stats1 partials. No LDS staging, no barriers.
__global__ __launch_bounds__(256) void k_conv1_v2(const float* __restrict__ x,
                                                  const float* __restrict__ w1,
                                                  float* __restrict__ y1,
                                                  float* __restrict__ partials) {
  int lane = threadIdx.x & 63;
  int wid = (blockIdx.x << 2) | (threadIdx.x >> 6);
  int seg = wid & 1;
  int strip = (wid >> 1) & (NSTRIP - 1);
  int b = wid >> 6;
  bool leftSeg = (seg == 0);
  int elane = leftSeg ? 63 : 0;
  int eoff = leftSeg ? 4 : -1;
  int c0 = (seg << 8) | (lane << 2);
  int h0 = strip * TH2;

  float wr[3][3][3][3];
#pragma unroll
  for (int o = 0; o < 3; ++o)
#pragma unroll
    for (int ci = 0; ci < 3; ++ci)
#pragma unroll
      for (int ky = 0; ky < 3; ++ky)
#pragma unroll
        for (int kx = 0; kx < 3; ++kx)
          wr[o][ci][ky][kx] = w1[((o * 3 + ci) * 3 + ky) * 3 + kx];

  const float* xb[3];
#pragma unroll
  for (int ci = 0; ci < 3; ++ci) xb[ci] = x + (size_t)(b * 3 + ci) * PLANE;
  float* yb = y1 + (size_t)(b * 3) * PLANE;

  FRow F[3][3];
  LRow N[3];
  {
    LRow P[3], Q[3];
#pragma unroll
    for (int ci = 0; ci < 3; ++ci) P[ci] = load_row(xb[ci], h0 - 1, c0, lane, elane, eoff);
#pragma unroll
    for (int ci = 0; ci < 3; ++ci) Q[ci] = load_row(xb[ci], h0, c0, lane, elane, eoff);
#pragma unroll
    for (int ci = 0; ci < 3; ++ci) N[ci] = load_row(xb[ci], h0 + 1, c0, lane, elane, eoff);
#pragma unroll
    for (int ci = 0; ci < 3; ++ci) {
      F[ci][0] = fin1(P[ci], lane, leftSeg);
      F[ci][1] = fin1(Q[ci], lane, leftSeg);
    }
  }

  float st[6] = {0.f, 0.f, 0.f, 0.f, 0.f, 0.f};
#pragma unroll 4
  for (int r = 0; r < TH2; ++r) {
#pragma unroll
    for (int ci = 0; ci < 3; ++ci) F[ci][2] = fin1(N[ci], lane, leftSeg);
    if (r < TH2 - 1) {  // issue next row's loads before the FMA block
#pragma unroll
      for (int ci = 0; ci < 3; ++ci) N[ci] = load_row(xb[ci], h0 + r + 2, c0, lane, elane, eoff);
    }
    float4 acc[3];
    acc[0] = make_float4(0.f, 0.f, 0.f, 0.f);
    acc[1] = make_float4(0.f, 0.f, 0.f, 0.f);
    acc[2] = make_float4(0.f, 0.f, 0.f, 0.f);
    conv_accum(F, wr, acc);

    int gh = h0 + r;
    float* yrow = yb + (size_t)gh * WW + c0;
#pragma unroll
    for (int co = 0; co < 3; ++co) {
      *(float4*)(yrow + (size_t)co * PLANE) = acc[co];
      st[co] += (acc[co].x + acc[co].y) + (acc[co].z + acc[co].w);
      st[3 + co] += fmaf(acc[co].x, acc[co].x, acc[co].y * acc[co].y) +
                    fmaf(acc[co].z, acc[co].z, acc[co].w * acc[co].w);
    }
#pragma unroll
    for (int ci = 0; ci < 3; ++ci) {
      F[ci][0] = F[ci][1];
      F[ci][1] = F[ci][2];
    }
  }
  block_reduce6_store(st, partials + (size_t)blockIdx.x * 6);
}

// P2: y1 -> z (register, bn1+rational) -> conv2 -> u + stats2 partials
__global__ __launch_bounds__(256) void k_conv2s_v2(const float* __restrict__ y1,
                                                   const float* __restrict__ w2,
                                                   const float* __restrict__ hdr,
                                                   const float* __restrict__ ar, const float* __restrict__ br,
                                                   const float* __restrict__ ag, const float* __restrict__ bg,
                                                   const float* __restrict__ ab_, const float* __restrict__ bb,
                                                   float* __restrict__ u,
                                                   float* __restrict__ partials) {
  int lane = threadIdx.x & 63;
  int wid = (blockIdx.x << 2) | (threadIdx.x >> 6);
  int seg = wid & 1;
  int strip = (wid >> 1) & (NSTRIP - 1);
  int b = wid >> 6;
  bool leftSeg = (seg == 0);
  int elane = leftSeg ? 63 : 0;
  int eoff = leftSeg ? 4 : -1;
  int c0 = (seg << 8) | (lane << 2);
  int h0 = strip * TH2;

  float sc1[3], sh1[3];
#pragma unroll
  for (int c = 0; c < 3; ++c) {
    sc1[c] = hdr[c];
    sh1[c] = hdr[3 + c];
  }
  float A[3][6], Bq[3][4];
#pragma unroll
  for (int i = 0; i < 6; ++i) { A[0][i] = ar[i]; A[1][i] = ag[i]; A[2][i] = ab_[i]; }
#pragma unroll
  for (int i = 0; i < 4; ++i) { Bq[0][i] = br[i]; Bq[1][i] = bg[i]; Bq[2][i] = bb[i]; }

  float wr[3][3][3][3];
#pragma unroll
  for (int o = 0; o < 3; ++o)
#pragma unroll
    for (int ci = 0; ci < 3; ++ci)
#pragma unroll
      for (int ky = 0; ky < 3; ++ky)
#pragma unroll
        for (int kx = 0; kx < 3; ++kx)
          wr[o][ci][ky][kx] = w2[((o * 3 + ci) * 3 + ky) * 3 + kx];

  const float* yb[3];
#pragma unroll
  for (int ci = 0; ci < 3; ++ci) yb[ci] = y1 + (size_t)(b * 3 + ci) * PLANE;
  float* ub = u + (size_t)(b * 3) * PLANE;

  FRow F[3][3];
  LRow N[3];
  {
    LRow P[3], Q[3];
#pragma unroll
    for (int ci = 0; ci < 3; ++ci) P[ci] = load_row(yb[ci], h0 - 1, c0, lane, elane, eoff);
#pragma unroll
    for (int ci = 0; ci < 3; ++ci) Q[ci] = load_row(yb[ci], h0, c0, lane, elane, eoff);
#pragma unroll
    for (int ci = 0; ci < 3; ++ci) N[ci] = load_row(yb[ci], h0 + 1, c0, lane, elane, eoff);
#pragma unroll
    for (int ci = 0; ci < 3; ++ci) {
      F[ci][0] = fin2(P[ci], lane, leftSeg, sc1[ci], sh1[ci], A[ci], Bq[ci]);
      F[ci][1] = fin2(Q[ci], lane, leftSeg, sc1[ci], sh1[ci], A[ci], Bq[ci]);
    }
  }

  float st[6] = {0.f, 0.f, 0.f, 0.f, 0.f, 0.f};
#pragma unroll 4
  for (int r = 0; r < TH2; ++r) {
#pragma unroll
    for (int ci = 0; ci < 3; ++ci)
      F[ci][2] = fin2(N[ci], lane, leftSeg, sc1[ci], sh1[ci], A[ci], Bq[ci]);
    if (r < TH2 - 1) {
#pragma unroll
      for (int ci = 0; ci < 3; ++ci) N[ci] = load_row(yb[ci], h0 + r + 2, c0, lane, elane, eoff);
    }
    float4 acc[3];
    acc[0] = make_float4(0.f, 0.f, 0.f, 0.f);
    acc[1] = make_float4(0.f, 0.f, 0.f, 0.f);
    acc[2] = make_float4(0.f, 0.f, 0.f, 0.f);
    conv_accum(F, wr, acc);

    int gh = h0 + r;
    float* urow = ub + (size_t)gh * WW + c0;
#pragma unroll
    for (int co = 0; co < 3; ++co) {
      *(float4*)(urow + (size_t)co * PLANE) = acc[co];
      st[co] += (acc[co].x + acc[co].y) + (acc[co].z + acc[co].w);
      st[3 + co] += fmaf(acc[co].x, acc[co].x, acc[co].y * acc[co].y) +
                    fmaf(acc[co].z, acc[co].z, acc[co].w * acc[co].w);
    }
#pragma unroll
    for (int ci = 0; ci < 3; ++ci) {
      F[ci][0] = F[ci][1];
      F[ci][1] = F[ci][2];
    }
  }
  block_reduce6_store(st, partials + (size_t)blockIdx.x * 6);
}

// P3: pointwise bn2 + residual + rational, in-place on u (=d_out)
// 8 independent float4 pairs per thread, loads issued up-front
__global__ __launch_bounds__(256) void k_pointwise2(float* __restrict__ u,
                                                    const float* __restrict__ x,
                                                    const float* __restrict__ hdr,
                                                    const float* __restrict__ ar, const float* __restrict__ br,
                                                    const float* __restrict__ ag, const float* __restrict__ bg,
                                                    const float* __restrict__ ab_, const float* __restrict__ bb) {
  int plane = blockIdx.y;  // 0..191 = b*3+c
  int c = plane % 3;
  const float* Ap = (c == 0) ? ar : ((c == 1) ? ag : ab_);
  const float* Bp = (c == 0) ? br : ((c == 1) ? bg : bb);
  float A[6], Bc[4];
#pragma unroll
  for (int i = 0; i < 6; ++i) A[i] = Ap[i];
#pragma unroll
  for (int i = 0; i < 4; ++i) Bc[i] = Bp[i];
  float sc2 = hdr[6 + c], sh2 = hdr[9 + c];

  size_t base = (size_t)plane * PLANE + (size_t)blockIdx.x * (256 * 8 * 4);
  const float4* xv = (const float4*)(x + base);
  float4* uv = (float4*)(u + base);
  float4 uu[8], xx[8];
#pragma unroll
  for (int k = 0; k < 8; ++k) uu[k] = uv[k * 256 + threadIdx.x];
#pragma unroll
  for (int k = 0; k < 8; ++k) xx[k] = xv[k * 256 + threadIdx.x];
#pragma unroll
  for (int k = 0; k < 8; ++k) {
    float4 o;
    o.x = ratf(fmaf(uu[k].x, sc2, sh2) + xx[k].x, A, Bc);
    o.y = ratf(fmaf(uu[k].y, sc2, sh2) + xx[k].y, A, Bc);
    o.z = ratf(fmaf(uu[k].z, sc2, sh2) + xx[k].z, A, Bc);
    o.w = ratf(fmaf(uu[k].w, sc2, sh2) + xx[k].w, A, Bc);
    uv[k * 256 + threadIdx.x] = o;
  }
}

// ======================= FALLBACK PATH (R2, proven) ========================

__global__ __launch_bounds__(NTHR) void k_stats1(const float* __restrict__ x,
                                                 const float* __restrict__ w1,
                                                 float* __restrict__ partials) {
  __shared__ float xs[3][X1_H][X1_W];
  int bid = blockIdx.x;
  int tx = bid & 7, ty = (bid >> 3) & 31, b = bid >> 8;
  int h0 = ty * TH, w0 = tx * TW;

  const int NE = 3 * X1_H * X1_W;
  for (int i = threadIdx.x; i < NE; i += NTHR) {
    int c = i / (X1_H * X1_W);
    int rem = i - c * (X1_H * X1_W);
    int r = rem / X1_W, cc = rem - r * X1_W;
    int gh = h0 - 1 + r, gw = w0 - 1 + cc;
    float v = 0.f;
    if ((unsigned)gh < HH && (unsigned)gw < WW)
      v = x[(((size_t)b * 3 + c) * HH + gh) * WW + gw];
    xs[c][r][cc] = v;
  }
  float wr[3][3][3][3];
#pragma unroll
  for (int o = 0; o < 3; ++o)
#pragma unroll
    for (int ci = 0; ci < 3; ++ci)
#pragma unroll
      for (int ky = 0; ky < 3; ++ky)
#pragma unroll
        for (int kx = 0; kx < 3; ++kx)
          wr[o][ci][ky][kx] = w1[((o * 3 + ci) * 3 + ky) * 3 + kx];
  __syncthreads();

  int cc = threadIdx.x & 63;
  int rr0 = (threadIdx.x >> 6) * 4;
  float acc[4][3] = {};
#pragma unroll
  for (int ci = 0; ci < 3; ++ci)
#pragma unroll
    for (int kx = 0; kx < 3; ++kx) {
      float v[6];
#pragma unroll
      for (int i = 0; i < 6; ++i) v[i] = xs[ci][rr0 + i][cc + kx];
#pragma unroll
      for (int o = 0; o < 4; ++o)
#pragma unroll
        for (int ky = 0; ky < 3; ++ky) {
          float vv = v[o + ky];
#pragma unroll
          for (int co = 0; co < 3; ++co) acc[o][co] = fmaf(wr[co][ci][ky][kx], vv, acc[o][co]);
        }
    }
  float s[6] = {0.f, 0.f, 0.f, 0.f, 0.f, 0.f};
#pragma unroll
  for (int o = 0; o < 4; ++o)
#pragma unroll
    for (int co = 0; co < 3; ++co) {
      float y = acc[o][co];
      s[co] += y;
      s[3 + co] += y * y;
    }
  block_reduce6_store(s, partials + (size_t)bid * 6);
}

template <bool FINAL>
__global__ __launch_bounds__(NTHR) void k_fused(const float* __restrict__ x,
                                                const float* __restrict__ w1,
                                                const float* __restrict__ w2,
                                                const float* __restrict__ hdr,
                                                const float* __restrict__ ar, const float* __restrict__ br,
                                                const float* __restrict__ ag, const float* __restrict__ bg,
                                                const float* __restrict__ ab_, const float* __restrict__ bb,
                                                float* __restrict__ dst) {
  __shared__ float xs[3][XT_H][XT_W];
  __shared__ float zs[3][ZT_H][ZT_W];
  int bid = blockIdx.x;
  int tx = bid & 7, ty = (bid >> 3) & 31, b = bid >> 8;
  int h0 = ty * TH, w0 = tx * TW;

  const int NE = 3 * XT_H * XT_W;
  for (int i = threadIdx.x; i < NE; i += NTHR) {
    int c = i / (XT_H * XT_W);
    int rem = i - c * (XT_H * XT_W);
    int r = rem / XT_W, cc = rem - r * XT_W;
    int gh = h0 - 2 + r, gw = w0 - 2 + cc;
    float v = 0.f;
    if ((unsigned)gh < HH && (unsigned)gw < WW)
      v = x[(((size_t)b * 3 + c) * HH + gh) * WW + gw];
    xs[c][r][cc] = v;
  }

  float scale1[3], shift1[3];
#pragma unroll
  for (int c = 0; c < 3; ++c) {
    scale1[c] = hdr[c];
    shift1[c] = hdr[3 + c];
  }
  float A[3][6], Bq[3][4];
#pragma unroll
  for (int i = 0; i < 6; ++i) { A[0][i] = ar[i]; A[1][i] = ag[i]; A[2][i] = ab_[i]; }
#pragma unroll
  for (int i = 0; i < 4; ++i) { Bq[0][i] = br[i]; Bq[1][i] = bg[i]; Bq[2][i] = bb[i]; }

  float wr[3][3][3][3];
#pragma unroll
  for (int o = 0; o < 3; ++o)
#pragma unroll
    for (int ci = 0; ci < 3; ++ci)
#pragma unroll
      for (int ky = 0; ky < 3; ++ky)
#pragma unroll
        for (int kx = 0; kx < 3; ++kx)
          wr[o][ci][ky][kx] = w1[((o * 3 + ci) * 3 + ky) * 3 + kx];
  __syncthreads();

  for (int i = threadIdx.x; i < ZT_H * ZT_W; i += NTHR) {
    int r = i / ZT_W, cc = i - r * ZT_W;
    int gh = h0 - 1 + r, gw = w0 - 1 + cc;
    float z0 = 0.f, z1 = 0.f, z2 = 0.f;
    if ((unsigned)gh < HH && (unsigned)gw < WW) {
      float a0 = 0.f, a1 = 0.f, a2 = 0.f;
#pragma unroll
      for (int ci = 0; ci < 3; ++ci)
#pragma unroll
        for (int ky = 0; ky < 3; ++ky)
#pragma unroll
          for (int kx = 0; kx < 3; ++kx) {
            float v = xs[ci][r + ky][cc + kx];
            a0 = fmaf(wr[0][ci][ky][kx], v, a0);
            a1 = fmaf(wr[1][ci][ky][kx], v, a1);
            a2 = fmaf(wr[2][ci][ky][kx], v, a2);
          }
      z0 = ratf(fmaf(a0, scale1[0], shift1[0]), A[0], Bq[0]);
      z1 = ratf(fmaf(a1, scale1[1], shift1[1]), A[1], Bq[1]);
      z2 = ratf(fmaf(a2, scale1[2], shift1[2]), A[2], Bq[2]);
    }
    zs[0][r][cc] = z0;
    zs[1][r][cc] = z1;
    zs[2][r][cc] = z2;
  }

#pragma unroll
  for (int o = 0; o < 3; ++o)
#pragma unroll
    for (int ci = 0; ci < 3; ++ci)
#pragma unroll
      for (int ky = 0; ky < 3; ++ky)
#pragma unroll
        for (int kx = 0; kx < 3; ++kx)
          wr[o][ci][ky][kx] = w2[((o * 3 + ci) * 3 + ky) * 3 + kx];
  __syncthreads();

  int cc = threadIdx.x & 63;
  int rr0 = (threadIdx.x >> 6) * 4;
  float acc[4][3] = {};
#pragma unroll
  for (int ci = 0; ci < 3; ++ci)
#pragma unroll
    for (int kx = 0; kx < 3; ++kx) {
      float v[6];
#pragma unroll
      for (int i = 0; i < 6; ++i) v[i] = zs[ci][rr0 + i][cc + kx];
#pragma unroll
      for (int o = 0; o < 4; ++o)
#pragma unroll
        for (int ky = 0; ky < 3; ++ky) {
          float vv = v[o + ky];
#pragma unroll
          for (int co = 0; co < 3; ++co) acc[o][co] = fmaf(wr[co][ci][ky][kx], vv, acc[o][co]);
        }
    }

  if constexpr (FINAL) {
    float scale2[3], shift2[3];
#pragma unroll
    for (int c = 0; c < 3; ++c) {
      scale2[c] = hdr[6 + c];
      shift2[c] = hdr[9 + c];
    }
#pragma unroll
    for (int o = 0; o < 4; ++o) {
      int rr = rr0 + o;
#pragma unroll
      for (int co = 0; co < 3; ++co) {
        float y = fmaf(acc[o][co], scale2[co], shift2[co]);
        float v = y + xs[co][rr + 2][cc + 2];
        dst[(((size_t)b * 3 + co) * HH + (h0 + rr)) * WW + (w0 + cc)] = ratf(v, A[co], Bq[co]);
      }
    }
  } else {
    float s[6] = {0.f, 0.f, 0.f, 0.f, 0.f, 0.f};
#pragma unroll
    for (int o = 0; o < 4; ++o)
#pragma unroll
      for (int co = 0; co < 3; ++co) {
        float y = acc[o][co];
        s[co] += y;
        s[3 + co] += y * y;
      }
    block_reduce6_store(s, dst + (size_t)bid * 6);
  }
}

extern "C" void kernel_launch(void* const* d_in, const int* in_sizes, int n_in,
                              void* d_out, int out_size, void* d_ws, size_t ws_size,
                              hipStream_t stream) {
  const float* x  = (const float*)d_in[0];
  const float* w1 = (const float*)d_in[1];
  const float* g1 = (const float*)d_in[2];
  const float* b1 = (const float*)d_in[3];
  const float* ar = (const float*)d_in[4];
  const float* br = (const float*)d_in[5];
  const float* ag = (const float*)d_in[6];
  const float* bg = (const float*)d_in[7];
  const float* ab = (const float*)d_in[8];
  const float* bb = (const float*)d_in[9];
  const float* w2 = (const float*)d_in[10];
  const float* g2 = (const float*)d_in[11];
  const float* b2 = (const float*)d_in[12];
  float* out = (float*)d_out;

  if (ws_size >= WS_FAST_BYTES) {
    // fast path: y1 in d_ws; u in d_out; part1 in d_out (consumed before u written)
    float* y1    = (float*)d_ws;
    float* part2 = (float*)d_ws + Y1_ELEMS;
    float* hdr   = part2 + (size_t)NPART * 6;  // 12 floats
    float* part1 = out;

    k_conv1_v2<<<dim3(NBLK2), dim3(256), 0, stream>>>(x, w1, y1, part1);
    k_reduce<<<dim3(1), dim3(256), 0, stream>>>(part1, NPART, g1, b1, hdr);
    k_conv2s_v2<<<dim3(NBLK2), dim3(256), 0, stream>>>(y1, w2, hdr, ar, br, ag, bg, ab, bb, out, part2);
    k_reduce<<<dim3(1), dim3(256), 0, stream>>>(part2, NPART, g2, b2, hdr + 6);
    k_pointwise2<<<dim3(PLANE / (256 * 8 * 4), NBATCH * 3), dim3(256), 0, stream>>>(
        out, x, hdr, ar, br, ag, bg, ab, bb);
  } else {
    // fallback: recompute path (R2)
    float* part1 = out;
    float* part2 = out + (size_t)NTILES * 6;
    float* hdr = (float*)d_ws;

    k_stats1<<<dim3(NTILES), dim3(NTHR), 0, stream>>>(x, w1, part1);
    k_reduce<<<dim3(1), dim3(256), 0, stream>>>(part1, NTILES, g1, b1, hdr);
    k_fused<false><<<dim3(NTILES), dim3(NTHR), 0, stream>>>(x, w1, w2, hdr, ar, br, ag, bg, ab, bb, part2);
    k_reduce<<<dim3(1), dim3(256), 0, stream>>>(part2, NTILES, g2, b2, hdr + 6);
    k_fused<true><<<dim3(NTILES), dim3(NTHR), 0, stream>>>(x, w1, w2, hdr, ar, br, ag, bg, ab, bb, out);
  }
}